// Round 8
// baseline (1476.959 us; speedup 1.0000x reference)
//
#include <hip/hip_runtime.h>
#include <stdint.h>

#define BB 8
#define NN 8192
#define NPOINT 1024
#define NSAMPLE 32
#define FPB 4                 // fps blocks per batch
#define PPB (NN / FPB)        // 2048 points per block
#define PPT (PPB / 256)       // 8 points per thread
#define XS 104   // x row stride in bf16 elems (cols: 0..63 feat, 64..66 xyz, 67..95 zero)
#define HS 72    // h / w2 / w3 row stride in bf16 elems (cols 0..63 used)

typedef short short8 __attribute__((ext_vector_type(8)));
typedef float floatx4 __attribute__((ext_vector_type(4)));

__device__ __forceinline__ unsigned short f2bf(float f) {
    unsigned u = __float_as_uint(f);
    unsigned r = u + 0x7FFFu + ((u >> 16) & 1u);   // RNE to bf16
    return (unsigned short)(r >> 16);
}

__device__ __forceinline__ unsigned long long u64max(unsigned long long a,
                                                     unsigned long long b) {
    return (a > b) ? a : b;
}

template <int CTRL, int RMASK>
__device__ __forceinline__ unsigned long long dpp_max_step(unsigned long long key) {
    int lo = (int)(unsigned int)(key & 0xffffffffull);
    int hi = (int)(unsigned int)(key >> 32);
    int tlo = __builtin_amdgcn_update_dpp(0, lo, CTRL, RMASK, 0xF, true);
    int thi = __builtin_amdgcn_update_dpp(0, hi, CTRL, RMASK, 0xF, true);
    unsigned long long t = ((unsigned long long)(unsigned int)thi << 32) |
                           (unsigned long long)(unsigned int)tlo;
    return u64max(key, t);
}

__device__ __forceinline__ unsigned long long dpp_wave_max(unsigned long long key) {
    key = dpp_max_step<0x111, 0xF>(key);  // row_shr:1
    key = dpp_max_step<0x112, 0xF>(key);  // row_shr:2
    key = dpp_max_step<0x114, 0xF>(key);  // row_shr:4
    key = dpp_max_step<0x118, 0xF>(key);  // row_shr:8
    key = dpp_max_step<0x142, 0xA>(key);  // row_bcast:15
    key = dpp_max_step<0x143, 0xC>(key);  // row_bcast:31
    return key;
}

// ---------------------------------------------------------------------------
// Kernel 0: zero the 128 mailbox slots (graph-safe init; d_ws is poisoned
// 0xAA before every timed launch).
// ---------------------------------------------------------------------------
__global__ void zero_mbox_kernel(unsigned long long* mbox) {
    if (threadIdx.x < BB * FPB * FPB) mbox[threadIdx.x] = 0ull;
}

// ---------------------------------------------------------------------------
// Kernel 1: farthest point sampling, 4 CUs per batch. Block blk handles
// batch b=blk&7 (round-robin XCD heuristic: batch's 4 blocks co-located),
// part=blk>>3 owns points [part*2048, part*2048+2048) in registers
// (8 pts/thread, ~60 VGPR, no spills); full xyz copy in LDS for the
// post-reduce coordinate broadcast. Per iteration: local 2-chain argmax
// (bit-exact __f*_rn math, strict > = lowest index on ties), DPP wave
// reduce, LDS block fold, then a global 4-block exchange via depth-1 SPSC
// mailboxes: writer atomicCAS(slot,0,key) spin, reader atomicExch(slot,0)
// spin. key = (dist_bits<<32)|~gidx is never 0, so zero = empty. Flow
// control (slot must be consumed before rewrite) makes skew<=1 iter and
// the protocol deadlock-free. Selection stream bit-identical to numpy.
// ---------------------------------------------------------------------------
__global__ __launch_bounds__(256) void fps_kernel(const float* __restrict__ xyz,
                                                  float* __restrict__ new_xyz,
                                                  unsigned long long* __restrict__ mbox) {
    __shared__ float sx[NN];
    __shared__ float sy[NN];
    __shared__ float sz[NN];
    __shared__ __align__(16) unsigned long long wred[2][4];
    __shared__ int s_cur[2];

    const int blk = blockIdx.x;
    const int b = blk & 7;                 // batch
    const int part = blk >> 3;             // 0..3
    const int t = threadIdx.x;
    const int lane = t & 63;
    const int wv = t >> 6;                 // 4 waves
    const float* base = xyz + (size_t)b * NN * 3;
    unsigned long long* mb = mbox + b * (FPB * FPB);   // [writer*4 + reader]

    // full copy to LDS (coordinate broadcast source)
    for (int p = t; p < NN; p += 256) {
        sx[p] = base[p * 3 + 0];
        sy[p] = base[p * 3 + 1];
        sz[p] = base[p * 3 + 2];
    }
    // own 2048 points in registers
    float px[PPT], py[PPT], pz[PPT], dist[PPT];
    const int pbase = part * PPB;
#pragma unroll
    for (int i = 0; i < PPT; ++i) {
        int p = pbase + t + (i << 8);
        px[i] = base[p * 3 + 0];
        py[i] = base[p * 3 + 1];
        pz[i] = base[p * 3 + 2];
        dist[i] = 1e10f;                   // f32(10000000000.0) exact
    }
    __syncthreads();

    float lx = sx[0], ly = sy[0], lz = sz[0];
    float* outb = new_xyz + (size_t)b * NPOINT * 3;
    if (part == 0 && t == 0) { outb[0] = lx; outb[1] = ly; outb[2] = lz; }

    for (int j = 1; j < NPOINT; ++j) {
        float bd0 = -1.0f, bd1 = -1.0f;
        int bi0 = 0, bi1 = 1;
#pragma unroll
        for (int i = 0; i < PPT; i += 2) {
            {   // even chain
                float dx = __fsub_rn(px[i], lx);
                float dy = __fsub_rn(py[i], ly);
                float dz = __fsub_rn(pz[i], lz);
                float d2 = __fadd_rn(__fadd_rn(__fmul_rn(dx, dx), __fmul_rn(dy, dy)),
                                     __fmul_rn(dz, dz));
                float dd = fminf(dist[i], d2);
                dist[i] = dd;
                bool gt = dd > bd0;
                bd0 = gt ? dd : bd0;
                bi0 = gt ? i : bi0;
            }
            {   // odd chain
                float dx = __fsub_rn(px[i + 1], lx);
                float dy = __fsub_rn(py[i + 1], ly);
                float dz = __fsub_rn(pz[i + 1], lz);
                float d2 = __fadd_rn(__fadd_rn(__fmul_rn(dx, dx), __fmul_rn(dy, dy)),
                                     __fmul_rn(dz, dz));
                float dd = fminf(dist[i + 1], d2);
                dist[i + 1] = dd;
                bool gt = dd > bd1;
                bd1 = gt ? dd : bd1;
                bi1 = gt ? (i + 1) : bi1;
            }
        }
        unsigned long long key0 =
            ((unsigned long long)__float_as_uint(bd0) << 32) |
            (unsigned long long)(~(unsigned int)(pbase + t + (bi0 << 8)));
        unsigned long long key1 =
            ((unsigned long long)__float_as_uint(bd1) << 32) |
            (unsigned long long)(~(unsigned int)(pbase + t + (bi1 << 8)));
        unsigned long long key = u64max(key0, key1);
        key = dpp_wave_max(key);
        if (lane == 63) wred[j & 1][wv] = key;
        __syncthreads();                                  // barrier A
        if (wv == 0) {
            const unsigned long long* wr = wred[j & 1];
            ulonglong2 q01 = *(const ulonglong2*)&wr[0];
            ulonglong2 q23 = *(const ulonglong2*)&wr[2];
            unsigned long long myk = u64max(u64max(q01.x, q01.y),
                                            u64max(q23.x, q23.y));
            // write phase: lanes 0..3 (skip self) post my block key to peers
            if (lane < FPB && lane != part) {
                while (atomicCAS(&mb[part * FPB + lane], 0ull, myk) != 0ull) {}
            }
            // read phase: lanes 4..7 collect the 4 block keys
            unsigned long long got = 0;
            if (lane >= 4 && lane < 4 + FPB) {
                int src = lane - 4;
                if (src == part) {
                    got = myk;
                } else {
                    do { got = atomicExch(&mb[src * FPB + part], 0ull); } while (got == 0ull);
                }
            }
            // fold lanes 4..7 -> lane 7 (zero-fill is identity for u64 max)
            got = dpp_max_step<0x111, 0xF>(got);
            got = dpp_max_step<0x112, 0xF>(got);
            if (lane == 7) s_cur[j & 1] = (int)(~(unsigned int)(got & 0xffffffffull));
        }
        __syncthreads();                                  // barrier B
        int cur = s_cur[j & 1];
        lx = sx[cur]; ly = sy[cur]; lz = sz[cur];         // LDS broadcast
        if (part == 0 && t == 0) {                        // fire-and-forget
            outb[j * 3 + 0] = lx;
            outb[j * 3 + 1] = ly;
            outb[j * 3 + 2] = lz;
        }
    }
}

// ---------------------------------------------------------------------------
// Kernel 2: ball query (separate light kernel: needs high occupancy to hide
// its serial chunk-scan latency — fusing it into the MLP kernel cost +125us
// in R7). 4 waves/block, one centroid per wave. First NSAMPLE in-radius
// indices ascending, padded with first hit.
// ---------------------------------------------------------------------------
__global__ __launch_bounds__(256) void ballq_kernel(const float* __restrict__ xyz,
                                                    const float* __restrict__ new_xyz,
                                                    int* __restrict__ gidx) {
    __shared__ int s_hits[4][NSAMPLE];
    const int t = threadIdx.x;
    const int lane = t & 63;
    const int wv = t >> 6;
    const int g = blockIdx.x * 4 + wv;
    const int bi = g >> 10;
    const float R2 = (float)(0.4 * 0.4);

    const float cx = new_xyz[g * 3 + 0];
    const float cy = new_xyz[g * 3 + 1];
    const float cz = new_xyz[g * 3 + 2];
    const float* base = xyz + (size_t)bi * NN * 3;

    int have = 0;
    for (int chunk = 0; chunk < (NN / 64) && have < NSAMPLE; ++chunk) {
        int p = (chunk << 6) + lane;
        float dx = __fsub_rn(cx, base[p * 3 + 0]);
        float dy = __fsub_rn(cy, base[p * 3 + 1]);
        float dz = __fsub_rn(cz, base[p * 3 + 2]);
        float d2 = __fadd_rn(__fadd_rn(__fmul_rn(dx, dx), __fmul_rn(dy, dy)),
                             __fmul_rn(dz, dz));
        bool in = d2 < R2;
        unsigned long long m = __ballot(in);
        int pre = __popcll(m & ((1ull << lane) - 1ull));
        int slot = have + pre;
        if (in && slot < NSAMPLE) s_hits[wv][slot] = p;
        have += (int)__popcll(m);
    }
    __syncthreads();
    if (lane < NSAMPLE) {
        int first = s_hits[wv][0];
        int v = (lane < have) ? s_hits[wv][lane] : first;
        gidx[(size_t)g * NSAMPLE + lane] = v;
    }
}

// ---------------------------------------------------------------------------
// Kernel 3: gather + 3-layer MLP via bf16 MFMA (16x16x32), fused max-pool.
// (R6 structure, 68KB LDS, 2 blocks/CU.)
// ---------------------------------------------------------------------------
__global__ __launch_bounds__(256) void mlp_mfma_kernel(
    const float* __restrict__ xyz, const float* __restrict__ features,
    const float* __restrict__ w1, const float* __restrict__ b1,
    const float* __restrict__ w2, const float* __restrict__ b2,
    const float* __restrict__ w3, const float* __restrict__ b3,
    const float* __restrict__ new_xyz, const int* __restrict__ gidx,
    float* __restrict__ out_feat) {
    __shared__ __align__(16) unsigned short s_x[128 * XS];    // 26624 B; later h2[128][HS]
    __shared__ __align__(16) unsigned short s_h[128 * HS];    // 18432 B
    __shared__ __align__(16) unsigned short s_w12[11264];     // w1[64][XS]@0, w2[64][HS]@6656; later w3[128][HS]@0
    __shared__ int s_gi[128];

    const int t = threadIdx.x;
    const int lane = t & 63;
    const int w = t >> 6;
    const int col = lane & 15;
    const int quad = lane >> 4;
    const int blk = blockIdx.x;
    const int bi = blk >> 8;              // 256 blocks per batch

    if (t < 128) s_gi[t] = gidx[blk * 128 + t];
    __syncthreads();

    // ---- stage w1, w2 + gather x ----
    {
        int o = t >> 2, part = t & 3;
        const float* w1r = w1 + o * 67;
#pragma unroll
        for (int i = 0; i < 26; ++i) {
            int c = part * 26 + i;
            float v = 0.0f;
            if (c < 64) v = w1r[3 + c];           // permuted: feats first
            else if (c < 67) v = w1r[c - 64];     // then xyz cols
            s_w12[o * XS + c] = f2bf(v);
        }
        const float* w2r = w2 + o * 64 + part * 16;
#pragma unroll
        for (int i = 0; i < 8; ++i) {
            unsigned pk = (unsigned)f2bf(w2r[2 * i]) |
                          ((unsigned)f2bf(w2r[2 * i + 1]) << 16);
            *(unsigned*)&s_w12[6656 + o * HS + part * 16 + 2 * i] = pk;
        }
    }
    {
        int k = t >> 1, half = t & 1;
        int row = s_gi[k];
        const float4* frow =
            (const float4*)(features + ((size_t)bi * NN + row) * 64) + half * 8;
        unsigned short* xr = &s_x[k * XS + half * 32];
#pragma unroll
        for (int i = 0; i < 8; ++i) {
            float4 v = frow[i];
            unsigned lo = (unsigned)f2bf(v.x) | ((unsigned)f2bf(v.y) << 16);
            unsigned hi = (unsigned)f2bf(v.z) | ((unsigned)f2bf(v.w) << 16);
            *(uint2*)(xr + i * 4) = make_uint2(lo, hi);
        }
    }
    if (t < 128) {
        int k = t;
        int row = s_gi[k];
        int gg = (blk << 2) + (k >> 5);
        const float* pr = xyz + ((size_t)bi * NN + row) * 3;
        const float* cr = new_xyz + (size_t)gg * 3;
        s_x[k * XS + 64] = f2bf(pr[0] - cr[0]);
        s_x[k * XS + 65] = f2bf(pr[1] - cr[1]);
        s_x[k * XS + 66] = f2bf(pr[2] - cr[2]);
        s_x[k * XS + 67] = 0;
        unsigned* z = (unsigned*)&s_x[k * XS + 68];
#pragma unroll
        for (int i = 0; i < 14; ++i) z[i] = 0;        // cols 68..95
    }
    __syncthreads();

    const int mbase = w * 32;

    // ---- Layer 1: [128 x 96] x [96 -> 64] ----
    floatx4 acc[2][4] = {};
    for (int kk = 0; kk < 3; ++kk) {
        short8 a0 = *(const short8*)&s_x[(mbase + col) * XS + kk * 32 + quad * 8];
        short8 a1 = *(const short8*)&s_x[(mbase + 16 + col) * XS + kk * 32 + quad * 8];
#pragma unroll
        for (int nt = 0; nt < 4; ++nt) {
            short8 b = *(const short8*)&s_w12[(nt * 16 + col) * XS + kk * 32 + quad * 8];
            acc[0][nt] = __builtin_amdgcn_mfma_f32_16x16x32_bf16(a0, b, acc[0][nt], 0, 0, 0);
            acc[1][nt] = __builtin_amdgcn_mfma_f32_16x16x32_bf16(a1, b, acc[1][nt], 0, 0, 0);
        }
    }
#pragma unroll
    for (int nt = 0; nt < 4; ++nt) {
        float bb = b1[nt * 16 + col];
#pragma unroll
        for (int mt = 0; mt < 2; ++mt)
#pragma unroll
            for (int r = 0; r < 4; ++r) {
                float v = fmaxf(acc[mt][nt][r] + bb, 0.0f);
                s_h[(mbase + mt * 16 + quad * 4 + r) * HS + nt * 16 + col] = f2bf(v);
            }
    }
    __syncthreads();

    // ---- Layer 2: [128 x 64] x [64 -> 64], h2 -> s_x region ----
    floatx4 acc2[2][4] = {};
    for (int kk = 0; kk < 2; ++kk) {
        short8 a0 = *(const short8*)&s_h[(mbase + col) * HS + kk * 32 + quad * 8];
        short8 a1 = *(const short8*)&s_h[(mbase + 16 + col) * HS + kk * 32 + quad * 8];
#pragma unroll
        for (int nt = 0; nt < 4; ++nt) {
            short8 b = *(const short8*)&s_w12[6656 + (nt * 16 + col) * HS + kk * 32 + quad * 8];
            acc2[0][nt] = __builtin_amdgcn_mfma_f32_16x16x32_bf16(a0, b, acc2[0][nt], 0, 0, 0);
            acc2[1][nt] = __builtin_amdgcn_mfma_f32_16x16x32_bf16(a1, b, acc2[1][nt], 0, 0, 0);
        }
    }
    unsigned short* s_h2 = s_x;  // x dead after L1
#pragma unroll
    for (int nt = 0; nt < 4; ++nt) {
        float bb = b2[nt * 16 + col];
#pragma unroll
        for (int mt = 0; mt < 2; ++mt)
#pragma unroll
            for (int r = 0; r < 4; ++r) {
                float v = fmaxf(acc2[mt][nt][r] + bb, 0.0f);
                s_h2[(mbase + mt * 16 + quad * 4 + r) * HS + nt * 16 + col] = f2bf(v);
            }
    }
    __syncthreads();   // h2 complete; all w2 reads done

    // ---- stage w3 [128][HS] over w1/w2 ----
    {
        int o = t >> 1, half = t & 1;
        const float* w3r = w3 + o * 64 + half * 32;
#pragma unroll
        for (int i = 0; i < 16; ++i) {
            unsigned pk = (unsigned)f2bf(w3r[2 * i]) |
                          ((unsigned)f2bf(w3r[2 * i + 1]) << 16);
            *(unsigned*)&s_w12[o * HS + half * 32 + 2 * i] = pk;
        }
    }
    __syncthreads();

    // ---- Layer 3: [128 x 64] x [64 -> 128], fused k-maxpool + bias + relu ----
    floatx4 c3[2][8] = {};
    for (int kk = 0; kk < 2; ++kk) {
        short8 a0 = *(const short8*)&s_h2[(mbase + col) * HS + kk * 32 + quad * 8];
        short8 a1 = *(const short8*)&s_h2[(mbase + 16 + col) * HS + kk * 32 + quad * 8];
#pragma unroll
        for (int nt = 0; nt < 8; ++nt) {
            short8 b = *(const short8*)&s_w12[(nt * 16 + col) * HS + kk * 32 + quad * 8];
            c3[0][nt] = __builtin_amdgcn_mfma_f32_16x16x32_bf16(a0, b, c3[0][nt], 0, 0, 0);
            c3[1][nt] = __builtin_amdgcn_mfma_f32_16x16x32_bf16(a1, b, c3[1][nt], 0, 0, 0);
        }
    }
    {
        int gg = (blk << 2) + w;
        float* ob = out_feat + (size_t)bi * (128 * 1024) + (gg & 1023);
#pragma unroll
        for (int nt = 0; nt < 8; ++nt) {
            float m = fmaxf(fmaxf(fmaxf(c3[0][nt][0], c3[0][nt][1]),
                                  fmaxf(c3[0][nt][2], c3[0][nt][3])),
                            fmaxf(fmaxf(c3[1][nt][0], c3[1][nt][1]),
                                  fmaxf(c3[1][nt][2], c3[1][nt][3])));
            m = fmaxf(m, __shfl_xor(m, 16));
            m = fmaxf(m, __shfl_xor(m, 32));
            if (lane < 16) {
                float v = fmaxf(m + b3[nt * 16 + lane], 0.0f);
                ob[(size_t)(nt * 16 + lane) * 1024] = v;
            }
        }
    }
}

extern "C" void kernel_launch(void* const* d_in, const int* in_sizes, int n_in,
                              void* d_out, int out_size, void* d_ws, size_t ws_size,
                              hipStream_t stream) {
    const float* xyz      = (const float*)d_in[0];
    const float* features = (const float*)d_in[1];
    const float* w1       = (const float*)d_in[2];
    const float* b1       = (const float*)d_in[3];
    const float* w2       = (const float*)d_in[4];
    const float* b2       = (const float*)d_in[5];
    const float* w3       = (const float*)d_in[6];
    const float* b3       = (const float*)d_in[7];

    float* out      = (float*)d_out;
    float* new_xyz  = out;                         // B*NPOINT*3
    float* out_feat = out + BB * NPOINT * 3;       // B*128*NPOINT
    // d_ws: mailboxes (first 1KB) are only live during fps; gidx (1MB,
    // written by ballq AFTER fps completes) aliases the same region.
    unsigned long long* mbox = (unsigned long long*)d_ws;
    int* gidx = (int*)d_ws;

    zero_mbox_kernel<<<1, 128, 0, stream>>>(mbox);
    fps_kernel<<<BB * FPB, 256, 0, stream>>>(xyz, new_xyz, mbox);
    ballq_kernel<<<(BB * NPOINT) / 4, 256, 0, stream>>>(xyz, new_xyz, gidx);
    mlp_mfma_kernel<<<(BB * NPOINT) / 4, 256, 0, stream>>>(xyz, features, w1, b1,
                                                           w2, b2, w3, b3,
                                                           new_xyz, gidx, out_feat);
}

// Round 9
// 1013.363 us; speedup vs baseline: 1.4575x; 1.4575x over previous
//
#include <hip/hip_runtime.h>
#include <stdint.h>

#define BB 8
#define NN 8192
#define NPOINT 1024
#define NSAMPLE 32
#define XS 104   // x row stride in bf16 elems (cols: 0..63 feat, 64..66 xyz, 67..95 zero)
#define HS 72    // h / w2 / w3 row stride in bf16 elems (cols 0..63 used)

typedef short short8 __attribute__((ext_vector_type(8)));
typedef float floatx4 __attribute__((ext_vector_type(4)));

__device__ __forceinline__ unsigned short f2bf(float f) {
    unsigned u = __float_as_uint(f);
    unsigned r = u + 0x7FFFu + ((u >> 16) & 1u);   // RNE to bf16
    return (unsigned short)(r >> 16);
}

__device__ __forceinline__ unsigned long long u64max(unsigned long long a,
                                                     unsigned long long b) {
    return (a > b) ? a : b;
}

template <int CTRL, int RMASK>
__device__ __forceinline__ unsigned long long dpp_max_step(unsigned long long key) {
    int lo = (int)(unsigned int)(key & 0xffffffffull);
    int hi = (int)(unsigned int)(key >> 32);
    int tlo = __builtin_amdgcn_update_dpp(0, lo, CTRL, RMASK, 0xF, true);
    int thi = __builtin_amdgcn_update_dpp(0, hi, CTRL, RMASK, 0xF, true);
    unsigned long long t = ((unsigned long long)(unsigned int)thi << 32) |
                           (unsigned long long)(unsigned int)tlo;
    return u64max(key, t);
}

__device__ __forceinline__ unsigned long long dpp_wave_max(unsigned long long key) {
    key = dpp_max_step<0x111, 0xF>(key);  // row_shr:1
    key = dpp_max_step<0x112, 0xF>(key);  // row_shr:2
    key = dpp_max_step<0x114, 0xF>(key);  // row_shr:4
    key = dpp_max_step<0x118, 0xF>(key);  // row_shr:8
    key = dpp_max_step<0x142, 0xA>(key);  // row_bcast:15
    key = dpp_max_step<0x143, 0xC>(key);  // row_bcast:31
    return key;
}

// ---------------------------------------------------------------------------
// MEGA KERNEL. Blocks 0..7: FPS (one per batch, R7 form — 1 block/CU due to
// 99KB LDS). Blocks 8..2055: consumers (b=i&7, g=i>>3), each handles 4
// centroids: spin on sel[] (relaxed agent atomics; payload=idx+1, poison
// 0xAA.. = not ready), then ball query + bf16-MFMA MLP + maxpool (R7 fused
// form — its exposed latency is hidden behind the fps-paced wait).
// Producer->consumer needs no fences: the single u32 IS the payload;
// consumers re-gather centroid coords from xyz (bit-identical to new_xyz).
// ---------------------------------------------------------------------------
__global__ __launch_bounds__(256) void mega_kernel(
    const float* __restrict__ xyz, const float* __restrict__ features,
    const float* __restrict__ w1, const float* __restrict__ b1,
    const float* __restrict__ w2, const float* __restrict__ b2,
    const float* __restrict__ w3, const float* __restrict__ b3,
    float* __restrict__ new_xyz, float* __restrict__ out_feat,
    unsigned* __restrict__ sel) {
    __shared__ __align__(16) char smem[98432];

    const int t = threadIdx.x;
    const int lane = t & 63;

    if (blockIdx.x < BB) {
        // =================== FPS (R7 structure + sel publish) ===============
        const int b = blockIdx.x;
        float* sx = (float*)smem;
        float* sy = sx + NN;
        float* sz = sy + NN;
        unsigned long long* wred = (unsigned long long*)(smem + 98304); // [2][4]
        const int wv = t >> 6;
        const float* base = xyz + (size_t)b * NN * 3;
        unsigned* selb = sel + b * NPOINT;

        float px[32], py[32], pz[32], dist[32];
#pragma unroll
        for (int i = 0; i < 32; ++i) {
            int p = t + (i << 8);               // coalesced glb, conflict-free LDS
            float x = base[p * 3 + 0];
            float y = base[p * 3 + 1];
            float z = base[p * 3 + 2];
            sx[p] = x; sy[p] = y; sz[p] = z;
            px[i] = x; py[i] = y; pz[i] = z;
            dist[i] = 1e10f;                    // f32(10000000000.0) exact
        }
        __syncthreads();

        float lx = sx[0], ly = sy[0], lz = sz[0];
        float* outb = new_xyz + (size_t)b * NPOINT * 3;
        if (t == 0) {
            outb[0] = lx; outb[1] = ly; outb[2] = lz;
            __hip_atomic_store(&selb[0], 1u, __ATOMIC_RELAXED,
                               __HIP_MEMORY_SCOPE_AGENT);
        }

        for (int j = 1; j < NPOINT; ++j) {
            float bd0 = -1.0f, bd1 = -1.0f;
            int bi0 = 0, bi1 = 1;
#pragma unroll
            for (int i = 0; i < 32; i += 2) {
                {   // even chain (bit-exact __f*_rn, strict > = lowest idx)
                    float dx = __fsub_rn(px[i], lx);
                    float dy = __fsub_rn(py[i], ly);
                    float dz = __fsub_rn(pz[i], lz);
                    float d2 = __fadd_rn(__fadd_rn(__fmul_rn(dx, dx), __fmul_rn(dy, dy)),
                                         __fmul_rn(dz, dz));
                    float dd = fminf(dist[i], d2);
                    dist[i] = dd;
                    bool gt = dd > bd0;
                    bd0 = gt ? dd : bd0;
                    bi0 = gt ? i : bi0;
                }
                {   // odd chain
                    float dx = __fsub_rn(px[i + 1], lx);
                    float dy = __fsub_rn(py[i + 1], ly);
                    float dz = __fsub_rn(pz[i + 1], lz);
                    float d2 = __fadd_rn(__fadd_rn(__fmul_rn(dx, dx), __fmul_rn(dy, dy)),
                                         __fmul_rn(dz, dz));
                    float dd = fminf(dist[i + 1], d2);
                    dist[i + 1] = dd;
                    bool gt = dd > bd1;
                    bd1 = gt ? dd : bd1;
                    bi1 = gt ? (i + 1) : bi1;
                }
            }
            unsigned long long key0 =
                ((unsigned long long)__float_as_uint(bd0) << 32) |
                (unsigned long long)(~(unsigned int)(t + (bi0 << 8)));
            unsigned long long key1 =
                ((unsigned long long)__float_as_uint(bd1) << 32) |
                (unsigned long long)(~(unsigned int)(t + (bi1 << 8)));
            unsigned long long key = u64max(key0, key1);
            key = dpp_wave_max(key);
            if (lane == 63) wred[(j & 1) * 4 + wv] = key;
            __syncthreads();
            int cur;
            {
                const unsigned long long* wr = &wred[(j & 1) * 4];
                ulonglong2 p01 = *(const ulonglong2*)&wr[0];
                ulonglong2 p23 = *(const ulonglong2*)&wr[2];
                unsigned long long m = u64max(u64max(p01.x, p01.y),
                                              u64max(p23.x, p23.y));
                cur = (int)(~(unsigned int)(m & 0xffffffffull));
            }
            lx = sx[cur]; ly = sy[cur]; lz = sz[cur];
            if (t == 0) {
                outb[j * 3 + 0] = lx;
                outb[j * 3 + 1] = ly;
                outb[j * 3 + 2] = lz;
                __hip_atomic_store(&selb[j], (unsigned)(cur + 1),
                                   __ATOMIC_RELAXED, __HIP_MEMORY_SCOPE_AGENT);
            }
        }
    } else {
        // =================== consumer: ballq + MFMA MLP =====================
        const int i = blockIdx.x - BB;
        const int b = i & 7;                   // batch
        const int g = i >> 3;                  // centroid group (4 centroids)
        unsigned short* s_x = (unsigned short*)smem;            // 128*XS
        unsigned short* s_h = (unsigned short*)(smem + 26624);  // 128*HS
        unsigned short* s_w12 = (unsigned short*)(smem + 45056);// 11264 elems
        int* s_gi = (int*)(smem + 67584);                       // 128
        int* s_sel4 = (int*)(smem + 68096);                     // 4

        const int w = t >> 6;
        const int col = lane & 15;
        const int quad = lane >> 4;

        // ---- stage w1, w2 (independent of fps progress) ----
        {
            int o = t >> 2, part = t & 3;
            const float* w1r = w1 + o * 67;
#pragma unroll
            for (int ii = 0; ii < 26; ++ii) {
                int c = part * 26 + ii;
                float v = 0.0f;
                if (c < 64) v = w1r[3 + c];           // permuted: feats first
                else if (c < 67) v = w1r[c - 64];     // then xyz cols
                s_w12[o * XS + c] = f2bf(v);
            }
            const float* w2r = w2 + o * 64 + part * 16;
#pragma unroll
            for (int ii = 0; ii < 8; ++ii) {
                unsigned pk = (unsigned)f2bf(w2r[2 * ii]) |
                              ((unsigned)f2bf(w2r[2 * ii + 1]) << 16);
                *(unsigned*)&s_w12[6656 + o * HS + part * 16 + 2 * ii] = pk;
            }
        }

        // ---- spin for the 4 centroid indices ----
        if (t < 4) {
            unsigned* sp = sel + b * NPOINT + (g << 2) + t;
            unsigned v;
            while ((( v = __hip_atomic_load(sp, __ATOMIC_RELAXED,
                                            __HIP_MEMORY_SCOPE_AGENT)) - 1u) > 8191u)
                __builtin_amdgcn_s_sleep(2);
            s_sel4[t] = (int)(v - 1u);
        }
        __syncthreads();

        // ---- ball query: wave w -> centroid s_sel4[w] ----
        {
            const int cidx = s_sel4[w];
            const float* base = xyz + (size_t)b * NN * 3;
            const float cx = base[cidx * 3 + 0];   // bit-identical to new_xyz
            const float cy = base[cidx * 3 + 1];
            const float cz = base[cidx * 3 + 2];
            const float R2 = (float)(0.4 * 0.4);   // 0.15999999642f

            int have = 0;
            for (int chunk = 0; chunk < (NN / 64) && have < NSAMPLE; ++chunk) {
                int p = (chunk << 6) + lane;
                float dx = __fsub_rn(cx, base[p * 3 + 0]);
                float dy = __fsub_rn(cy, base[p * 3 + 1]);
                float dz = __fsub_rn(cz, base[p * 3 + 2]);
                float d2 = __fadd_rn(__fadd_rn(__fmul_rn(dx, dx), __fmul_rn(dy, dy)),
                                     __fmul_rn(dz, dz));
                bool in = d2 < R2;
                unsigned long long m = __ballot(in);
                int pre = __popcll(m & ((1ull << lane) - 1ull));
                int slot = have + pre;
                if (in && slot < NSAMPLE) s_gi[w * NSAMPLE + slot] = p;
                have += (int)__popcll(m);
            }
            if (lane < NSAMPLE) {
                int first = s_gi[w * NSAMPLE];    // centroid always hits
                int v = (lane < have) ? s_gi[w * NSAMPLE + lane] : first;
                s_gi[w * NSAMPLE + lane] = v;
            }
        }
        __syncthreads();

        // ---- gather x = [feat(64) | xyz_rel(3) | zeros] in bf16 ----
        {
            int k = t >> 1, half = t & 1;
            int row = s_gi[k];
            const float4* frow =
                (const float4*)(features + ((size_t)b * NN + row) * 64) + half * 8;
            unsigned short* xr = &s_x[k * XS + half * 32];
#pragma unroll
            for (int ii = 0; ii < 8; ++ii) {
                float4 v = frow[ii];
                unsigned lo = (unsigned)f2bf(v.x) | ((unsigned)f2bf(v.y) << 16);
                unsigned hi = (unsigned)f2bf(v.z) | ((unsigned)f2bf(v.w) << 16);
                *(uint2*)(xr + ii * 4) = make_uint2(lo, hi);
            }
        }
        if (t < 128) {
            int k = t;
            int row = s_gi[k];
            int cidx = s_sel4[k >> 5];
            const float* pr = xyz + ((size_t)b * NN + row) * 3;
            const float* cr = xyz + ((size_t)b * NN + cidx) * 3;
            s_x[k * XS + 64] = f2bf(pr[0] - cr[0]);
            s_x[k * XS + 65] = f2bf(pr[1] - cr[1]);
            s_x[k * XS + 66] = f2bf(pr[2] - cr[2]);
            s_x[k * XS + 67] = 0;
            unsigned* z = (unsigned*)&s_x[k * XS + 68];
#pragma unroll
            for (int ii = 0; ii < 14; ++ii) z[ii] = 0;    // cols 68..95
        }
        __syncthreads();

        const int mbase = w * 32;

        // ---- Layer 1: [128 x 96] x [96 -> 64] ----
        floatx4 acc[2][4] = {};
        for (int kk = 0; kk < 3; ++kk) {
            short8 a0 = *(const short8*)&s_x[(mbase + col) * XS + kk * 32 + quad * 8];
            short8 a1 = *(const short8*)&s_x[(mbase + 16 + col) * XS + kk * 32 + quad * 8];
#pragma unroll
            for (int nt = 0; nt < 4; ++nt) {
                short8 bfr = *(const short8*)&s_w12[(nt * 16 + col) * XS + kk * 32 + quad * 8];
                acc[0][nt] = __builtin_amdgcn_mfma_f32_16x16x32_bf16(a0, bfr, acc[0][nt], 0, 0, 0);
                acc[1][nt] = __builtin_amdgcn_mfma_f32_16x16x32_bf16(a1, bfr, acc[1][nt], 0, 0, 0);
            }
        }
#pragma unroll
        for (int nt = 0; nt < 4; ++nt) {
            float bb = b1[nt * 16 + col];
#pragma unroll
            for (int mt = 0; mt < 2; ++mt)
#pragma unroll
                for (int r = 0; r < 4; ++r) {
                    float v = fmaxf(acc[mt][nt][r] + bb, 0.0f);
                    s_h[(mbase + mt * 16 + quad * 4 + r) * HS + nt * 16 + col] = f2bf(v);
                }
        }
        __syncthreads();

        // ---- Layer 2: [128 x 64] x [64 -> 64], h2 -> s_x region ----
        floatx4 acc2[2][4] = {};
        for (int kk = 0; kk < 2; ++kk) {
            short8 a0 = *(const short8*)&s_h[(mbase + col) * HS + kk * 32 + quad * 8];
            short8 a1 = *(const short8*)&s_h[(mbase + 16 + col) * HS + kk * 32 + quad * 8];
#pragma unroll
            for (int nt = 0; nt < 4; ++nt) {
                short8 bfr = *(const short8*)&s_w12[6656 + (nt * 16 + col) * HS + kk * 32 + quad * 8];
                acc2[0][nt] = __builtin_amdgcn_mfma_f32_16x16x32_bf16(a0, bfr, acc2[0][nt], 0, 0, 0);
                acc2[1][nt] = __builtin_amdgcn_mfma_f32_16x16x32_bf16(a1, bfr, acc2[1][nt], 0, 0, 0);
            }
        }
        unsigned short* s_h2 = s_x;  // x dead after L1
#pragma unroll
        for (int nt = 0; nt < 4; ++nt) {
            float bb = b2[nt * 16 + col];
#pragma unroll
            for (int mt = 0; mt < 2; ++mt)
#pragma unroll
                for (int r = 0; r < 4; ++r) {
                    float v = fmaxf(acc2[mt][nt][r] + bb, 0.0f);
                    s_h2[(mbase + mt * 16 + quad * 4 + r) * HS + nt * 16 + col] = f2bf(v);
                }
        }
        __syncthreads();   // h2 complete; all w2 reads done

        // ---- stage w3 [128][HS] over w1/w2 ----
        {
            int o = t >> 1, half = t & 1;
            const float* w3r = w3 + o * 64 + half * 32;
#pragma unroll
            for (int ii = 0; ii < 16; ++ii) {
                unsigned pk = (unsigned)f2bf(w3r[2 * ii]) |
                              ((unsigned)f2bf(w3r[2 * ii + 1]) << 16);
                *(unsigned*)&s_w12[o * HS + half * 32 + 2 * ii] = pk;
            }
        }
        __syncthreads();

        // ---- Layer 3: [128 x 64] x [64 -> 128], fused maxpool+bias+relu ----
        floatx4 c3[2][8] = {};
        for (int kk = 0; kk < 2; ++kk) {
            short8 a0 = *(const short8*)&s_h2[(mbase + col) * HS + kk * 32 + quad * 8];
            short8 a1 = *(const short8*)&s_h2[(mbase + 16 + col) * HS + kk * 32 + quad * 8];
#pragma unroll
            for (int nt = 0; nt < 8; ++nt) {
                short8 bfr = *(const short8*)&s_w12[(nt * 16 + col) * HS + kk * 32 + quad * 8];
                c3[0][nt] = __builtin_amdgcn_mfma_f32_16x16x32_bf16(a0, bfr, c3[0][nt], 0, 0, 0);
                c3[1][nt] = __builtin_amdgcn_mfma_f32_16x16x32_bf16(a1, bfr, c3[1][nt], 0, 0, 0);
            }
        }
        {
            int gg = (g << 2) + w;
            float* ob = out_feat + (size_t)b * (128 * 1024) + gg;
#pragma unroll
            for (int nt = 0; nt < 8; ++nt) {
                float m = fmaxf(fmaxf(fmaxf(c3[0][nt][0], c3[0][nt][1]),
                                      fmaxf(c3[0][nt][2], c3[0][nt][3])),
                                fmaxf(fmaxf(c3[1][nt][0], c3[1][nt][1]),
                                      fmaxf(c3[1][nt][2], c3[1][nt][3])));
                m = fmaxf(m, __shfl_xor(m, 16));
                m = fmaxf(m, __shfl_xor(m, 32));
                if (lane < 16) {
                    float v = fmaxf(m + b3[nt * 16 + lane], 0.0f);
                    ob[(size_t)(nt * 16 + lane) * 1024] = v;
                }
            }
        }
    }
}

extern "C" void kernel_launch(void* const* d_in, const int* in_sizes, int n_in,
                              void* d_out, int out_size, void* d_ws, size_t ws_size,
                              hipStream_t stream) {
    const float* xyz      = (const float*)d_in[0];
    const float* features = (const float*)d_in[1];
    const float* w1       = (const float*)d_in[2];
    const float* b1       = (const float*)d_in[3];
    const float* w2       = (const float*)d_in[4];
    const float* b2       = (const float*)d_in[5];
    const float* w3       = (const float*)d_in[6];
    const float* b3       = (const float*)d_in[7];

    float* out      = (float*)d_out;
    float* new_xyz  = out;                         // B*NPOINT*3
    float* out_feat = out + BB * NPOINT * 3;       // B*128*NPOINT
    unsigned* sel   = (unsigned*)d_ws;             // B*NPOINT u32; poison = not-ready

    mega_kernel<<<BB + (BB * NPOINT) / 4, 256, 0, stream>>>(
        xyz, features, w1, b1, w2, b2, w3, b3, new_xyz, out_feat, sel);
}